// Round 2
// baseline (4550.141 us; speedup 1.0000x reference)
//
#include <hip/hip_runtime.h>
#include <algorithm>
#include <cstdint>

// Problem constants (fixed by setup_inputs)
#define Nn 8192
#define Mm 8192
#define Dd 512
#define Cc 128

#define BT 128   // block tile (n and m)
#define TK 16    // k-chunk

// ---- workspace layout (bytes) ----
#define WS_SR     0ull
#define WS_SC     65536ull
#define WS_GHIST  131072ull
#define WS_CTR    393216ull
#define WS_FINAL  393280ull
#define WS_CAND   458816ull
#define CAP_STORE 4194304ull
#define WS_INNER  (WS_CAND + CAP_STORE * 16ull)            // 67567680
#define WS_NEED_STORE (WS_INNER + (size_t)Nn * Mm * 4ull)  // ~320.4 MB
#define FCAP      4096u

// Column mapping: thread (tx) owns cols {tx*4..tx*4+3} and {64+tx*4..64+tx*4+3}.
// This makes the SB fragment b128 reads span all 32 banks 2-way (free, m136)
// instead of the old tx*8 mapping's 4-way conflict.
__device__ __forceinline__ int jcol(int tx, int j) {
  return (j < 4) ? tx * 4 + j : 64 + tx * 4 + (j - 4);
}

// ---------------------------------------------------------------------------
// Shared inner-GEMM core: C[128x128] tile of A(n,d)·B(m,d)^T, two-level fp32
// accumulation (16-chunk inner, 32-chunk outer — numerics identical to R1),
// register-prefetch software pipeline to hide global latency.
// ---------------------------------------------------------------------------
__device__ __forceinline__ void inner_gemm(const float* __restrict__ A,
                                           const float* __restrict__ B,
                                           int n0, int m0, int tid,
                                           float (*SA)[BT], float (*SB)[BT],
                                           float acc2[8][8]) {
  const int tx = tid & 15, ty = tid >> 4;
  const int lrow = tid >> 1;       // 0..127
  const int lk8  = (tid & 1) * 8;  // 0 or 8
  const float* Ap = A + (size_t)(n0 + lrow) * Dd + lk8;
  const float* Bp = B + (size_t)(m0 + lrow) * Dd + lk8;

#pragma unroll
  for (int i = 0; i < 8; ++i)
#pragma unroll
    for (int j = 0; j < 8; ++j) acc2[i][j] = 0.0f;

  float4 pa0 = *(const float4*)(Ap);
  float4 pa1 = *(const float4*)(Ap + 4);
  float4 pb0 = *(const float4*)(Bp);
  float4 pb1 = *(const float4*)(Bp + 4);

  for (int k0 = 0; k0 < Dd; k0 += TK) {
    __syncthreads();  // previous chunk's compute done -> LDS reusable
    {
      const float ar[8] = {pa0.x,pa0.y,pa0.z,pa0.w,pa1.x,pa1.y,pa1.z,pa1.w};
      const float br[8] = {pb0.x,pb0.y,pb0.z,pb0.w,pb1.x,pb1.y,pb1.z,pb1.w};
#pragma unroll
      for (int s = 0; s < 8; ++s) { SA[lk8 + s][lrow] = ar[s]; SB[lk8 + s][lrow] = br[s]; }
    }
    if (k0 + TK < Dd) {  // prefetch next chunk; completes during compute below
      pa0 = *(const float4*)(Ap + k0 + TK);
      pa1 = *(const float4*)(Ap + k0 + TK + 4);
      pb0 = *(const float4*)(Bp + k0 + TK);
      pb1 = *(const float4*)(Bp + k0 + TK + 4);
    }
    __syncthreads();
    float acc1[8][8];
#pragma unroll
    for (int i = 0; i < 8; ++i)
#pragma unroll
      for (int j = 0; j < 8; ++j) acc1[i][j] = 0.0f;
#pragma unroll
    for (int kk = 0; kk < TK; ++kk) {
      const float4 av0 = *(const float4*)&SA[kk][ty * 8];
      const float4 av1 = *(const float4*)&SA[kk][ty * 8 + 4];
      const float4 bv0 = *(const float4*)&SB[kk][tx * 4];
      const float4 bv1 = *(const float4*)&SB[kk][64 + tx * 4];
      const float a[8] = {av0.x,av0.y,av0.z,av0.w,av1.x,av1.y,av1.z,av1.w};
      const float b[8] = {bv0.x,bv0.y,bv0.z,bv0.w,bv1.x,bv1.y,bv1.z,bv1.w};
#pragma unroll
      for (int i = 0; i < 8; ++i)
#pragma unroll
        for (int j = 0; j < 8; ++j) acc1[i][j] = fmaf(a[i], b[j], acc1[i][j]);
    }
#pragma unroll
    for (int i = 0; i < 8; ++i)
#pragma unroll
      for (int j = 0; j < 8; ++j) acc2[i][j] += acc1[i][j];
  }
}

// ---------------------------------------------------------------------------
// Overlap GEMM: cas0[C][N] (k-major already) x cas1[C][M], same fragment map.
// ---------------------------------------------------------------------------
__device__ __forceinline__ void overlap_gemm(const float* __restrict__ C0,
                                             const float* __restrict__ C1,
                                             int n0, int m0, int tid,
                                             float (*SA)[BT], float (*SB)[BT],
                                             float ov2[8][8]) {
  const int tx = tid & 15, ty = tid >> 4;
  const int sc = tid >> 4;          // c-row within chunk
  const int sn = (tid & 15) * 8;    // column offset
  const float* c0p = C0 + (size_t)sc * Nn + n0 + sn;
  const float* c1p = C1 + (size_t)sc * Mm + m0 + sn;

#pragma unroll
  for (int i = 0; i < 8; ++i)
#pragma unroll
    for (int j = 0; j < 8; ++j) ov2[i][j] = 0.0f;

  float4 pa0 = *(const float4*)(c0p);
  float4 pa1 = *(const float4*)(c0p + 4);
  float4 pb0 = *(const float4*)(c1p);
  float4 pb1 = *(const float4*)(c1p + 4);

  for (int c0i = 0; c0i < Cc; c0i += TK) {
    __syncthreads();
    *(float4*)&SA[sc][sn] = pa0; *(float4*)&SA[sc][sn + 4] = pa1;
    *(float4*)&SB[sc][sn] = pb0; *(float4*)&SB[sc][sn + 4] = pb1;
    if (c0i + TK < Cc) {
      pa0 = *(const float4*)(c0p + (size_t)(c0i + TK) * Nn);
      pa1 = *(const float4*)(c0p + (size_t)(c0i + TK) * Nn + 4);
      pb0 = *(const float4*)(c1p + (size_t)(c0i + TK) * Mm);
      pb1 = *(const float4*)(c1p + (size_t)(c0i + TK) * Mm + 4);
    }
    __syncthreads();
    float ov1[8][8];
#pragma unroll
    for (int i = 0; i < 8; ++i)
#pragma unroll
      for (int j = 0; j < 8; ++j) ov1[i][j] = 0.0f;
#pragma unroll
    for (int kk = 0; kk < TK; ++kk) {
      const float4 av0 = *(const float4*)&SA[kk][ty * 8];
      const float4 av1 = *(const float4*)&SA[kk][ty * 8 + 4];
      const float4 bv0 = *(const float4*)&SB[kk][tx * 4];
      const float4 bv1 = *(const float4*)&SB[kk][64 + tx * 4];
      const float a[8] = {av0.x,av0.y,av0.z,av0.w,av1.x,av1.y,av1.z,av1.w};
      const float b[8] = {bv0.x,bv0.y,bv0.z,bv0.w,bv1.x,bv1.y,bv1.z,bv1.w};
#pragma unroll
      for (int i = 0; i < 8; ++i)
#pragma unroll
        for (int j = 0; j < 8; ++j) ov1[i][j] = fmaf(a[i], b[j], ov1[i][j]);
    }
#pragma unroll
    for (int i = 0; i < 8; ++i)
#pragma unroll
      for (int j = 0; j < 8; ++j) ov2[i][j] += ov1[i][j];
  }
}

// ---------------------------------------------------------------------------
// Pass 1: inner GEMM -> (optional fp32 store to ws) -> exp row/col sums (f64)
// ---------------------------------------------------------------------------
template<bool STORE>
__global__ __launch_bounds__(256, 2) void k_pass1(const float* __restrict__ A,
                                                  const float* __restrict__ B,
                                                  double* __restrict__ Sr,
                                                  double* __restrict__ Sc,
                                                  float* __restrict__ inner) {
  __shared__ float SA[TK][BT];
  __shared__ float SB[TK][BT];
  __shared__ double csum[BT];
  const int tid = threadIdx.x;
  const int tx = tid & 15, ty = tid >> 4;
  const int n0 = blockIdx.y * BT, m0 = blockIdx.x * BT;

  float acc2[8][8];
  inner_gemm(A, B, n0, m0, tid, SA, SB, acc2);

  if (STORE) {
#pragma unroll
    for (int i = 0; i < 8; ++i) {
      float* rowp = inner + (size_t)(n0 + ty * 8 + i) * Mm + m0;
      *(float4*)(rowp + tx * 4)      = make_float4(acc2[i][0], acc2[i][1], acc2[i][2], acc2[i][3]);
      *(float4*)(rowp + 64 + tx * 4) = make_float4(acc2[i][4], acc2[i][5], acc2[i][6], acc2[i][7]);
    }
  }

  if (tid < BT) csum[tid] = 0.0;
  __syncthreads();

  float ev[8][8];
#pragma unroll
  for (int i = 0; i < 8; ++i)
#pragma unroll
    for (int j = 0; j < 8; ++j) ev[i][j] = expf(2.0f * acc2[i][j] - 2.0f);

  // row sums: the 16 lanes of a width-16 shuffle group share ty -> one f64
  // global atomic per row per block (was 16-way LDS f64 atomic contention)
#pragma unroll
  for (int i = 0; i < 8; ++i) {
    float r = 0.0f;
#pragma unroll
    for (int j = 0; j < 8; ++j) r += ev[i][j];
    double v = (double)r;
    v += __shfl_xor(v, 1, 16);
    v += __shfl_xor(v, 2, 16);
    v += __shfl_xor(v, 4, 16);
    v += __shfl_xor(v, 8, 16);
    if (tx == 0) atomicAdd(&Sr[n0 + ty * 8 + i], v);
  }
  // col sums: reduce the 4 ty-groups within each wave, then 4 LDS atomics/col
#pragma unroll
  for (int j = 0; j < 8; ++j) {
    float c = 0.0f;
#pragma unroll
    for (int i = 0; i < 8; ++i) c += ev[i][j];
    double v = (double)c;
    v += __shfl_xor(v, 16, 64);
    v += __shfl_xor(v, 32, 64);
    if ((tid & 63) < 16) atomicAdd(&csum[jcol(tx, j)], v);
  }
  __syncthreads();
  if (tid < BT) atomicAdd(&Sc[m0 + tid], csum[tid]);
}

// ---------------------------------------------------------------------------
// Kernel 2: Sr/Sc -> reciprocals in place
// ---------------------------------------------------------------------------
__global__ void k_recip(double* __restrict__ Sr, double* __restrict__ Sc) {
  const int i = blockIdx.x * 256 + threadIdx.x;
  if (i < Nn) Sr[i] = 1.0 / Sr[i];
  if (i < Mm) Sc[i] = 1.0 / Sc[i];
}

// ---------------------------------------------------------------------------
// Pass 2: (reload stored inner | recompute) + overlap GEMM + f64 score +
// per-tile candidate push with device-scope running threshold.
// ---------------------------------------------------------------------------
template<bool RELOAD>
__global__ __launch_bounds__(256, 2) void k_pass2(const float* __restrict__ A,
                                                  const float* __restrict__ B,
                                                  const float* __restrict__ C0,
                                                  const float* __restrict__ C1,
                                                  const double* __restrict__ invSr,
                                                  const double* __restrict__ invSc,
                                                  const float* __restrict__ inner,
                                                  uint4* __restrict__ cand,
                                                  unsigned int* __restrict__ ctr,
                                                  unsigned int cap) {
  __shared__ float SA[TK][BT];
  __shared__ float SB[TK][BT];
  __shared__ unsigned int h1[256];
  __shared__ unsigned int scn[256];
  __shared__ unsigned int sh_misc[4];
  const int tid = threadIdx.x;
  const int tx = tid & 15, ty = tid >> 4;
  const int n0 = blockIdx.y * BT, m0 = blockIdx.x * BT;

  float acc2[8][8];
  if (RELOAD) {
    // issue all 16 loads up-front; latency hides under the overlap GEMM
#pragma unroll
    for (int i = 0; i < 8; ++i) {
      const float* rowp = inner + (size_t)(n0 + ty * 8 + i) * Mm + m0;
      *(float4*)&acc2[i][0] = *(const float4*)(rowp + tx * 4);
      *(float4*)&acc2[i][4] = *(const float4*)(rowp + 64 + tx * 4);
    }
  } else {
    inner_gemm(A, B, n0, m0, tid, SA, SB, acc2);
  }

  float ov2[8][8];
  overlap_gemm(C0, C1, n0, m0, tid, SA, SB, ov2);

  double isr[8], isc[8];
#pragma unroll
  for (int i = 0; i < 8; ++i) isr[i] = invSr[n0 + ty * 8 + i];
#pragma unroll
  for (int j = 0; j < 8; ++j) isc[j] = invSc[m0 + jcol(tx, j)];

  unsigned int sbits[8][8];
#pragma unroll
  for (int i = 0; i < 8; ++i)
#pragma unroll
    for (int j = 0; j < 8; ++j) {
      const double e = exp(2.0 * (double)acc2[i][j] - 2.0);
      const double s = e * e * isr[i] * isc[j] * (double)ov2[i][j];
      sbits[i][j] = __float_as_uint((float)s);  // s > 0 -> monotone bits
    }

  // ---------------- two-level (8+8 bit) block histogram threshold ----------
  h1[tid] = 0;
  __syncthreads();
#pragma unroll
  for (int i = 0; i < 8; ++i)
#pragma unroll
    for (int j = 0; j < 8; ++j) atomicAdd(&h1[sbits[i][j] >> 24], 1u);
  __syncthreads();
  if (tid == 0) {
    unsigned cum = 0, cb = 0, above = 0;
    for (int b = 255; b >= 0; --b) {
      const unsigned nc = cum + h1[b];
      if (nc >= 256u) { cb = (unsigned)b; above = cum; break; }
      cum = nc;
    }
    sh_misc[0] = cb; sh_misc[1] = above;
  }
  __syncthreads();
  const unsigned cb = sh_misc[0], above = sh_misc[1];
  __syncthreads();
  h1[tid] = 0;
  __syncthreads();
#pragma unroll
  for (int i = 0; i < 8; ++i)
#pragma unroll
    for (int j = 0; j < 8; ++j)
      if ((sbits[i][j] >> 24) == cb) atomicAdd(&h1[(sbits[i][j] >> 16) & 0xFFu], 1u);
  __syncthreads();
  if (tid == 0) {
    unsigned cum = above, tb = cb << 8;
    for (int b = 255; b >= 0; --b) {
      cum += h1[b];
      if (cum >= 256u) { tb = (cb << 8) | (unsigned)b; break; }
    }
    const unsigned old = atomicMax(&ctr[2], tb);  // device-scope running bound
    sh_misc[2] = tb > old ? tb : old;
  }
  __syncthreads();
  const unsigned tb16 = sh_misc[2];

  // ---------------- push candidates (block-aggregated offsets) -------------
  unsigned cnt = 0;
#pragma unroll
  for (int i = 0; i < 8; ++i)
#pragma unroll
    for (int j = 0; j < 8; ++j) cnt += ((sbits[i][j] >> 16) >= tb16) ? 1u : 0u;
  scn[tid] = cnt;
  __syncthreads();
  if (tid == 0) {
    unsigned run = 0;
    for (int t = 0; t < 256; ++t) { const unsigned c = scn[t]; scn[t] = run; run += c; }
    sh_misc[3] = atomicAdd(&ctr[0], run);
  }
  __syncthreads();
  unsigned pos = sh_misc[3] + scn[tid];
#pragma unroll
  for (int i = 0; i < 8; ++i)
#pragma unroll
    for (int j = 0; j < 8; ++j) {
      if ((sbits[i][j] >> 16) >= tb16) {
        if (pos < cap) {
          const double e = exp(2.0 * (double)acc2[i][j] - 2.0);
          const double s = e * e * isr[i] * isc[j] * (double)ov2[i][j];
          const unsigned long long db = (unsigned long long)__double_as_longlong(s);
          const unsigned idxv = ((unsigned)(n0 + ty * 8 + i) << 13) | (unsigned)(m0 + jcol(tx, j));
          cand[pos] = make_uint4((unsigned)(db & 0xFFFFFFFFull),
                                 (unsigned)(db >> 32), idxv, sbits[i][j]);
        }
        ++pos;
      }
    }
}

// ---------------------------------------------------------------------------
// Kernel 4: global 65536-bin histogram of candidate keys
// ---------------------------------------------------------------------------
__global__ void k_ghist(const uint4* __restrict__ cand,
                        const unsigned int* __restrict__ ctr,
                        unsigned int cap, unsigned int* __restrict__ ghist) {
  const unsigned n = min(ctr[0], cap);
  const unsigned stride = gridDim.x * blockDim.x;
  for (unsigned i = blockIdx.x * blockDim.x + threadIdx.x; i < n; i += stride)
    atomicAdd(&ghist[cand[i].w >> 16], 1u);
}

// ---------------------------------------------------------------------------
// Kernel 5: find global threshold bin (suffix count >= 256)
// ---------------------------------------------------------------------------
__global__ __launch_bounds__(256) void k_thresh(const unsigned int* __restrict__ ghist,
                                                unsigned int* __restrict__ ctr) {
  __shared__ unsigned int gsum[256];
  const int tid = threadIdx.x;
  unsigned s = 0;
  const int base = tid * 256;
  for (int b = 0; b < 256; ++b) s += ghist[base + b];
  gsum[tid] = s;
  __syncthreads();
  if (tid == 0) {
    unsigned cum = 0, g = 0, above = 0;
    for (int t = 255; t >= 0; --t) {
      const unsigned nc = cum + gsum[t];
      if (nc >= 256u) { g = (unsigned)t; above = cum; break; }
      cum = nc;
    }
    unsigned tb = g * 256u, c2 = above;
    for (int b = (int)g * 256 + 255; b >= (int)g * 256; --b) {
      c2 += ghist[b];
      if (c2 >= 256u) { tb = (unsigned)b; break; }
    }
    ctr[3] = tb;
  }
}

// ---------------------------------------------------------------------------
// Kernel 6: collect survivors
// ---------------------------------------------------------------------------
__global__ void k_collect(const uint4* __restrict__ cand,
                          unsigned int* __restrict__ ctr,
                          unsigned int cap, uint4* __restrict__ fin) {
  const unsigned n = min(ctr[0], cap);
  const unsigned tb = ctr[3];
  const unsigned stride = gridDim.x * blockDim.x;
  for (unsigned i = blockIdx.x * blockDim.x + threadIdx.x; i < n; i += stride) {
    const uint4 c = cand[i];
    if ((c.w >> 16) >= tb) {
      const unsigned p = atomicAdd(&ctr[1], 1u);
      if (p < FCAP) fin[p] = c;
    }
  }
}

// ---------------------------------------------------------------------------
// Kernel 7: single-block bitonic sort over next-pow2(n) (f64 desc, idx asc)
// ---------------------------------------------------------------------------
__global__ __launch_bounds__(256) void k_sort(const uint4* __restrict__ fin,
                                              const unsigned int* __restrict__ ctr,
                                              float* __restrict__ out) {
  __shared__ unsigned long long kk[FCAP];
  __shared__ unsigned int id[FCAP];
  const int tid = threadIdx.x;
  const unsigned n = min(ctr[1], FCAP);
  unsigned np2 = 256;
  while (np2 < n) np2 <<= 1;
  for (unsigned i = tid; i < np2; i += 256) {
    if (i < n) {
      const uint4 c = fin[i];
      kk[i] = ((unsigned long long)c.y << 32) | (unsigned long long)c.x;
      id[i] = c.z;
    } else {
      kk[i] = 0ull;
      id[i] = 0xFFFFFFFFu;
    }
  }
  __syncthreads();
  for (unsigned k2 = 2; k2 <= np2; k2 <<= 1) {
    for (unsigned j = k2 >> 1; j > 0; j >>= 1) {
      for (unsigned i = tid; i < np2; i += 256) {
        const unsigned l = i ^ j;
        if (l > i) {
          const unsigned long long ka = kk[i], kb = kk[l];
          const unsigned ia = id[i], ib = id[l];
          const bool aBefore = (ka > kb) || (ka == kb && ia < ib);
          const bool dsc = (i & k2) == 0;
          const bool sw = dsc ? !aBefore : aBefore;
          if (sw) { kk[i] = kb; kk[l] = ka; id[i] = ib; id[l] = ia; }
        }
      }
      __syncthreads();
    }
  }
  {
    const unsigned long long kv = kk[tid];
    const unsigned ix = id[tid];
    const double s = __longlong_as_double((long long)kv);
    out[tid]        = (float)(ix >> 13);      // ref_corr_indices
    out[256 + tid]  = (float)(ix & 8191u);    // src_corr_indices
    out[512 + tid]  = (float)s;               // corr_scores
  }
}

// ---------------------------------------------------------------------------
extern "C" void kernel_launch(void* const* d_in, const int* in_sizes, int n_in,
                              void* d_out, int out_size, void* d_ws, size_t ws_size,
                              hipStream_t stream) {
  (void)in_sizes; (void)n_in; (void)out_size;
  const float* ref = (const float*)d_in[0];
  const float* src = (const float*)d_in[1];
  const float* c0  = (const float*)d_in[2];
  const float* c1  = (const float*)d_in[3];
  char* ws = (char*)d_ws;
  double* Sr = (double*)(ws + WS_SR);
  double* Sc = (double*)(ws + WS_SC);
  unsigned int* ghist = (unsigned int*)(ws + WS_GHIST);
  unsigned int* ctr   = (unsigned int*)(ws + WS_CTR);
  uint4* fin   = (uint4*)(ws + WS_FINAL);
  uint4* cand  = (uint4*)(ws + WS_CAND);
  float* inner = (float*)(ws + WS_INNER);

  const bool store = ws_size >= (size_t)WS_NEED_STORE;
  unsigned int cap = 0;
  if (store) {
    cap = (unsigned int)CAP_STORE;
  } else if (ws_size > (size_t)WS_CAND + 16) {
    cap = (unsigned int)std::min<size_t>((ws_size - WS_CAND) / 16, (size_t)(8u << 20));
  }

  // zero Sr, Sc, ghist, ctr
  hipMemsetAsync(d_ws, 0, (size_t)WS_FINAL, stream);

  dim3 grid(Mm / BT, Nn / BT);
  if (store) {
    k_pass1<true><<<grid, 256, 0, stream>>>(ref, src, Sr, Sc, inner);
    k_recip<<<32, 256, 0, stream>>>(Sr, Sc);
    k_pass2<true><<<grid, 256, 0, stream>>>(ref, src, c0, c1, Sr, Sc, inner, cand, ctr, cap);
  } else {
    k_pass1<false><<<grid, 256, 0, stream>>>(ref, src, Sr, Sc, nullptr);
    k_recip<<<32, 256, 0, stream>>>(Sr, Sc);
    k_pass2<false><<<grid, 256, 0, stream>>>(ref, src, c0, c1, Sr, Sc, nullptr, cand, ctr, cap);
  }
  k_ghist<<<256, 256, 0, stream>>>(cand, ctr, cap, ghist);
  k_thresh<<<1, 256, 0, stream>>>(ghist, ctr);
  k_collect<<<256, 256, 0, stream>>>(cand, ctr, cap, fin);
  k_sort<<<1, 256, 0, stream>>>(fin, ctr, (float*)d_out);
}

// Round 4
// 4327.005 us; speedup vs baseline: 1.0516x; 1.0516x over previous
//
#include <hip/hip_runtime.h>
#include <algorithm>
#include <cstdint>

// Problem constants (fixed by setup_inputs)
#define Nn 8192
#define Mm 8192
#define Dd 512
#define Cc 128

#define BT 128   // block tile (n and m)
#define TK 16    // k-chunk

// ---- workspace layout (bytes) ----
#define WS_SR     0ull
#define WS_SC     65536ull
#define WS_GHIST  131072ull
#define WS_CTR    393216ull
#define WS_FINAL  393280ull
#define WS_CANDNS 458816ull                                  // cand region, no-store path
#define WS_INNER  458816ull
#define WS_CAND   (WS_INNER + (size_t)Nn * Mm * 4ull)        // 268894272
#define WS_NEED_STORE (WS_CAND + (2ull << 20) * 16ull)       // inner + >=2M cand entries
#define FCAP      4096u

// Column swizzle for 16-wide tx groups: thread tx owns cols {tx*4..+3} and
// {64+tx*4..+3} -> SB b128 fragment reads are 2-way bank aliased (free, m136).
__device__ __forceinline__ int jcol(int tx, int j) {
  return (j < 4) ? tx * 4 + j : 64 + tx * 4 + (j - 4);
}

// ---------------------------------------------------------------------------
// Pass 1: inner GEMM (512 thr, 4x8/thread, TWO-LEVEL fp32 accumulation —
// bitwise-identical per-element op sequence to the R1/R2-validated kernels:
// 16-fma chain per 16-k chunk, then one add into acc2, chunks in order).
// Low live-register count (~100) so no scratch spills at 512 threads.
// Then optional store of the raw inner products + exp row/col sums (f64).
// ---------------------------------------------------------------------------
template<bool STORE>
__global__ __launch_bounds__(512, 2) void k_pass1(const float* __restrict__ A,
                                                  const float* __restrict__ B,
                                                  double* __restrict__ Sr,
                                                  double* __restrict__ Sc,
                                                  float* __restrict__ inner) {
  __shared__ float SA[TK][BT];
  __shared__ float SB[TK][BT];
  __shared__ double csum[BT];
  const int tid = threadIdx.x;
  const int tx = tid & 15;        // column group (8 cols via jcol)
  const int ty = tid >> 4;        // 0..31 -> rows ty*4..ty*4+3
  const int n0 = blockIdx.y * BT, m0 = blockIdx.x * BT;
  const int lrow = tid >> 2;      // 0..127 staging row
  const int lk4  = (tid & 3) * 4; // 0,4,8,12 staging k-offset
  const float* Ap = A + (size_t)(n0 + lrow) * Dd + lk4;
  const float* Bp = B + (size_t)(m0 + lrow) * Dd + lk4;

  float acc2[4][8];
#pragma unroll
  for (int i = 0; i < 4; ++i)
#pragma unroll
    for (int j = 0; j < 8; ++j) acc2[i][j] = 0.0f;

  float4 pa = *(const float4*)(Ap);
  float4 pb = *(const float4*)(Bp);

  for (int k0 = 0; k0 < Dd; k0 += TK) {
    __syncthreads();
    SA[lk4 + 0][lrow] = pa.x; SA[lk4 + 1][lrow] = pa.y;
    SA[lk4 + 2][lrow] = pa.z; SA[lk4 + 3][lrow] = pa.w;
    SB[lk4 + 0][lrow] = pb.x; SB[lk4 + 1][lrow] = pb.y;
    SB[lk4 + 2][lrow] = pb.z; SB[lk4 + 3][lrow] = pb.w;
    if (k0 + TK < Dd) {  // prefetch next chunk during compute
      pa = *(const float4*)(Ap + k0 + TK);
      pb = *(const float4*)(Bp + k0 + TK);
    }
    __syncthreads();
    float acc1[4][8];
#pragma unroll
    for (int i = 0; i < 4; ++i)
#pragma unroll
      for (int j = 0; j < 8; ++j) acc1[i][j] = 0.0f;
#pragma unroll
    for (int kk = 0; kk < TK; ++kk) {
      const float4 av  = *(const float4*)&SA[kk][ty * 4];
      const float4 bv0 = *(const float4*)&SB[kk][tx * 4];
      const float4 bv1 = *(const float4*)&SB[kk][64 + tx * 4];
      const float a[4] = {av.x, av.y, av.z, av.w};
      const float b[8] = {bv0.x,bv0.y,bv0.z,bv0.w,bv1.x,bv1.y,bv1.z,bv1.w};
#pragma unroll
      for (int i = 0; i < 4; ++i)
#pragma unroll
        for (int j = 0; j < 8; ++j) acc1[i][j] = fmaf(a[i], b[j], acc1[i][j]);
    }
#pragma unroll
    for (int i = 0; i < 4; ++i)
#pragma unroll
      for (int j = 0; j < 8; ++j) acc2[i][j] += acc1[i][j];
  }

  if (tid < BT) csum[tid] = 0.0;
  __syncthreads();

  float cp[8];
#pragma unroll
  for (int j = 0; j < 8; ++j) cp[j] = 0.0f;

#pragma unroll
  for (int i = 0; i < 4; ++i) {
    if (STORE) {
      float* rowp = inner + (size_t)(n0 + ty * 4 + i) * Mm + m0;
      *(float4*)(rowp + tx * 4)      = make_float4(acc2[i][0], acc2[i][1], acc2[i][2], acc2[i][3]);
      *(float4*)(rowp + 64 + tx * 4) = make_float4(acc2[i][4], acc2[i][5], acc2[i][6], acc2[i][7]);
    }
    float r = 0.0f;
#pragma unroll
    for (int j = 0; j < 8; ++j) {
      const float e = expf(2.0f * acc2[i][j] - 2.0f);
      r += e;
      cp[j] += e;
    }
    double v = (double)r;
    v += __shfl_xor(v, 1, 16);
    v += __shfl_xor(v, 2, 16);
    v += __shfl_xor(v, 4, 16);
    v += __shfl_xor(v, 8, 16);
    if (tx == 0) atomicAdd(&Sr[n0 + ty * 4 + i], v);
  }
  // col sums: reduce over the wave's 4 ty values, then LDS, then global
#pragma unroll
  for (int j = 0; j < 8; ++j) {
    double v = (double)cp[j];
    v += __shfl_xor(v, 16, 64);
    v += __shfl_xor(v, 32, 64);
    if ((tid & 63) < 16) atomicAdd(&csum[jcol(tx, j)], v);
  }
  __syncthreads();
  if (tid < BT) atomicAdd(&Sc[m0 + tid], csum[tid]);
}

// ---------------------------------------------------------------------------
__global__ void k_recip(double* __restrict__ Sr, double* __restrict__ Sc) {
  const int i = blockIdx.x * 256 + threadIdx.x;
  if (i < Nn) Sr[i] = 1.0 / Sr[i];
  if (i < Mm) Sc[i] = 1.0 / Sc[i];
}

// ---------------------------------------------------------------------------
// Pass 2 (store path): 1024 thr, 4x4/thread — reload stored inner (bitwise =
// pass1 acc2), overlap GEMM, f64 score, histogram threshold, candidate push.
// Col mapping per thread: {tx*2, tx*2+1, 64+tx*2, 64+tx*2+1} (2-way LDS alias).
// ---------------------------------------------------------------------------
__global__ __launch_bounds__(1024, 4) void k_pass2_reload(
    const float* __restrict__ C0, const float* __restrict__ C1,
    const double* __restrict__ invSr, const double* __restrict__ invSc,
    const float* __restrict__ inner, uint4* __restrict__ cand,
    unsigned int* __restrict__ ctr, unsigned int cap) {
  __shared__ float SA[TK][BT];
  __shared__ float SB[TK][BT];
  __shared__ unsigned int h1[256];
  __shared__ unsigned int scn[1024];
  __shared__ unsigned int sh_misc[4];
  const int tid = threadIdx.x;
  const int tx = tid & 31, ty = tid >> 5;   // 32x32 thread grid, 4x4 each
  const int n0 = blockIdx.y * BT, m0 = blockIdx.x * BT;

  // issue inner reload up-front; latency hides under the overlap GEMM
  float acc[4][4];
#pragma unroll
  for (int i = 0; i < 4; ++i) {
    const float* rowp = inner + (size_t)(n0 + ty * 4 + i) * Mm + m0;
    const float2 lo = *(const float2*)(rowp + tx * 2);
    const float2 hi = *(const float2*)(rowp + 64 + tx * 2);
    acc[i][0] = lo.x; acc[i][1] = lo.y; acc[i][2] = hi.x; acc[i][3] = hi.y;
  }

  // ---- overlap GEMM ----
  float ov[4][4];
#pragma unroll
  for (int i = 0; i < 4; ++i)
#pragma unroll
    for (int j = 0; j < 4; ++j) ov[i][j] = 0.0f;
  {
    const int srow = tid >> 6;         // 0..15
    const int scol = (tid & 63) * 2;   // 0..126
    const float* c0p = C0 + (size_t)srow * Nn + n0 + scol;
    const float* c1p = C1 + (size_t)srow * Mm + m0 + scol;
    float2 pa = *(const float2*)c0p;
    float2 pb = *(const float2*)c1p;
    for (int c0i = 0; c0i < Cc; c0i += TK) {
      __syncthreads();
      *(float2*)&SA[srow][scol] = pa;
      *(float2*)&SB[srow][scol] = pb;
      if (c0i + TK < Cc) {
        pa = *(const float2*)(c0p + (size_t)(c0i + TK) * Nn);
        pb = *(const float2*)(c1p + (size_t)(c0i + TK) * Mm);
      }
      __syncthreads();
#pragma unroll
      for (int kk = 0; kk < TK; ++kk) {
        const float4 av  = *(const float4*)&SA[kk][ty * 4];
        const float2 bv0 = *(const float2*)&SB[kk][tx * 2];
        const float2 bv1 = *(const float2*)&SB[kk][64 + tx * 2];
        const float a[4] = {av.x, av.y, av.z, av.w};
        const float b[4] = {bv0.x, bv0.y, bv1.x, bv1.y};
#pragma unroll
        for (int i = 0; i < 4; ++i)
#pragma unroll
          for (int j = 0; j < 4; ++j) ov[i][j] = fmaf(a[i], b[j], ov[i][j]);
      }
    }
  }

  // column index for local j
  int colj[4];
#pragma unroll
  for (int j = 0; j < 4; ++j) colj[j] = (j < 2) ? tx * 2 + j : 64 + tx * 2 + (j - 2);

  // ---- f64 score -> f32 key bits ----
  double isr[4], isc[4];
#pragma unroll
  for (int i = 0; i < 4; ++i) isr[i] = invSr[n0 + ty * 4 + i];
#pragma unroll
  for (int j = 0; j < 4; ++j) isc[j] = invSc[m0 + colj[j]];

  unsigned int sbits[4][4];
#pragma unroll
  for (int i = 0; i < 4; ++i)
#pragma unroll
    for (int j = 0; j < 4; ++j) {
      const double e = exp(2.0 * (double)acc[i][j] - 2.0);
      const double s = e * e * isr[i] * isc[j] * (double)ov[i][j];
      sbits[i][j] = __float_as_uint((float)s);
    }

  // ---- two-level (8+8 bit) block histogram threshold over 16384 elems ----
  if (tid < 256) h1[tid] = 0;
  __syncthreads();
#pragma unroll
  for (int i = 0; i < 4; ++i)
#pragma unroll
    for (int j = 0; j < 4; ++j) atomicAdd(&h1[sbits[i][j] >> 24], 1u);
  __syncthreads();
  if (tid == 0) {
    unsigned cum = 0, cb = 0, above = 0;
    for (int b = 255; b >= 0; --b) {
      const unsigned nc = cum + h1[b];
      if (nc >= 256u) { cb = (unsigned)b; above = cum; break; }
      cum = nc;
    }
    sh_misc[0] = cb; sh_misc[1] = above;
  }
  __syncthreads();
  const unsigned cb = sh_misc[0], above = sh_misc[1];
  __syncthreads();
  if (tid < 256) h1[tid] = 0;
  __syncthreads();
#pragma unroll
  for (int i = 0; i < 4; ++i)
#pragma unroll
    for (int j = 0; j < 4; ++j)
      if ((sbits[i][j] >> 24) == cb) atomicAdd(&h1[(sbits[i][j] >> 16) & 0xFFu], 1u);
  __syncthreads();
  if (tid == 0) {
    unsigned cum = above, tb = cb << 8;
    for (int b = 255; b >= 0; --b) {
      cum += h1[b];
      if (cum >= 256u) { tb = (cb << 8) | (unsigned)b; break; }
    }
    const unsigned old = atomicMax(&ctr[2], tb);  // device-scope running bound
    sh_misc[2] = tb > old ? tb : old;
  }
  __syncthreads();
  const unsigned tb16 = sh_misc[2];

  // ---- candidate push, block-aggregated offsets (1024-wide scan) ----
  unsigned cnt = 0;
#pragma unroll
  for (int i = 0; i < 4; ++i)
#pragma unroll
    for (int j = 0; j < 4; ++j) cnt += ((sbits[i][j] >> 16) >= tb16) ? 1u : 0u;
  scn[tid] = cnt;
  __syncthreads();
  for (int off = 1; off < 1024; off <<= 1) {
    const unsigned v = scn[tid];
    const unsigned add = (tid >= off) ? scn[tid - off] : 0u;
    __syncthreads();
    scn[tid] = v + add;
    __syncthreads();
  }
  if (tid == 0) sh_misc[3] = atomicAdd(&ctr[0], scn[1023]);
  __syncthreads();
  unsigned pos = sh_misc[3] + scn[tid] - cnt;
#pragma unroll
  for (int i = 0; i < 4; ++i)
#pragma unroll
    for (int j = 0; j < 4; ++j) {
      if ((sbits[i][j] >> 16) >= tb16) {
        if (pos < cap) {
          const double e = exp(2.0 * (double)acc[i][j] - 2.0);
          const double s = e * e * isr[i] * isc[j] * (double)ov[i][j];
          const unsigned long long db = (unsigned long long)__double_as_longlong(s);
          const unsigned idxv = ((unsigned)(n0 + ty * 4 + i) << 13) | (unsigned)(m0 + colj[j]);
          cand[pos] = make_uint4((unsigned)(db & 0xFFFFFFFFull),
                                 (unsigned)(db >> 32), idxv, sbits[i][j]);
        }
        ++pos;
      }
    }
}

// ---------------------------------------------------------------------------
// Fallback path (no store): R2-proven 256-thr 8x8 two-level recompute kernels.
// Correctness-only path; spills acceptable.
// ---------------------------------------------------------------------------
__device__ __forceinline__ void inner_gemm_256(const float* __restrict__ A,
                                               const float* __restrict__ B,
                                               int n0, int m0, int tid,
                                               float (*SA)[BT], float (*SB)[BT],
                                               float acc2[8][8]) {
  const int tx = tid & 15, ty = tid >> 4;
  const int lrow = tid >> 1;
  const int lk8  = (tid & 1) * 8;
  const float* Ap = A + (size_t)(n0 + lrow) * Dd + lk8;
  const float* Bp = B + (size_t)(m0 + lrow) * Dd + lk8;

#pragma unroll
  for (int i = 0; i < 8; ++i)
#pragma unroll
    for (int j = 0; j < 8; ++j) acc2[i][j] = 0.0f;

  float4 pa0 = *(const float4*)(Ap);
  float4 pa1 = *(const float4*)(Ap + 4);
  float4 pb0 = *(const float4*)(Bp);
  float4 pb1 = *(const float4*)(Bp + 4);

  for (int k0 = 0; k0 < Dd; k0 += TK) {
    __syncthreads();
    {
      const float ar[8] = {pa0.x,pa0.y,pa0.z,pa0.w,pa1.x,pa1.y,pa1.z,pa1.w};
      const float br[8] = {pb0.x,pb0.y,pb0.z,pb0.w,pb1.x,pb1.y,pb1.z,pb1.w};
#pragma unroll
      for (int s = 0; s < 8; ++s) { SA[lk8 + s][lrow] = ar[s]; SB[lk8 + s][lrow] = br[s]; }
    }
    if (k0 + TK < Dd) {
      pa0 = *(const float4*)(Ap + k0 + TK);
      pa1 = *(const float4*)(Ap + k0 + TK + 4);
      pb0 = *(const float4*)(Bp + k0 + TK);
      pb1 = *(const float4*)(Bp + k0 + TK + 4);
    }
    __syncthreads();
    float acc1[8][8];
#pragma unroll
    for (int i = 0; i < 8; ++i)
#pragma unroll
      for (int j = 0; j < 8; ++j) acc1[i][j] = 0.0f;
#pragma unroll
    for (int kk = 0; kk < TK; ++kk) {
      const float4 av0 = *(const float4*)&SA[kk][ty * 8];
      const float4 av1 = *(const float4*)&SA[kk][ty * 8 + 4];
      const float4 bv0 = *(const float4*)&SB[kk][tx * 4];
      const float4 bv1 = *(const float4*)&SB[kk][64 + tx * 4];
      const float a[8] = {av0.x,av0.y,av0.z,av0.w,av1.x,av1.y,av1.z,av1.w};
      const float b[8] = {bv0.x,bv0.y,bv0.z,bv0.w,bv1.x,bv1.y,bv1.z,bv1.w};
#pragma unroll
      for (int i = 0; i < 8; ++i)
#pragma unroll
        for (int j = 0; j < 8; ++j) acc1[i][j] = fmaf(a[i], b[j], acc1[i][j]);
    }
#pragma unroll
    for (int i = 0; i < 8; ++i)
#pragma unroll
      for (int j = 0; j < 8; ++j) acc2[i][j] += acc1[i][j];
  }
}

__device__ __forceinline__ void overlap_gemm_256(const float* __restrict__ C0,
                                                 const float* __restrict__ C1,
                                                 int n0, int m0, int tid,
                                                 float (*SA)[BT], float (*SB)[BT],
                                                 float ov[8][8]) {
  const int tx = tid & 15, ty = tid >> 4;
  const int sc = tid >> 4;
  const int sn = (tid & 15) * 8;
  const float* c0p = C0 + (size_t)sc * Nn + n0 + sn;
  const float* c1p = C1 + (size_t)sc * Mm + m0 + sn;

#pragma unroll
  for (int i = 0; i < 8; ++i)
#pragma unroll
    for (int j = 0; j < 8; ++j) ov[i][j] = 0.0f;

  float4 pa0 = *(const float4*)(c0p);
  float4 pa1 = *(const float4*)(c0p + 4);
  float4 pb0 = *(const float4*)(c1p);
  float4 pb1 = *(const float4*)(c1p + 4);

  for (int c0i = 0; c0i < Cc; c0i += TK) {
    __syncthreads();
    *(float4*)&SA[sc][sn] = pa0; *(float4*)&SA[sc][sn + 4] = pa1;
    *(float4*)&SB[sc][sn] = pb0; *(float4*)&SB[sc][sn + 4] = pb1;
    if (c0i + TK < Cc) {
      pa0 = *(const float4*)(c0p + (size_t)(c0i + TK) * Nn);
      pa1 = *(const float4*)(c0p + (size_t)(c0i + TK) * Nn + 4);
      pb0 = *(const float4*)(c1p + (size_t)(c0i + TK) * Mm);
      pb1 = *(const float4*)(c1p + (size_t)(c0i + TK) * Mm + 4);
    }
    __syncthreads();
#pragma unroll
    for (int kk = 0; kk < TK; ++kk) {
      const float4 av0 = *(const float4*)&SA[kk][ty * 8];
      const float4 av1 = *(const float4*)&SA[kk][ty * 8 + 4];
      const float4 bv0 = *(const float4*)&SB[kk][tx * 4];
      const float4 bv1 = *(const float4*)&SB[kk][64 + tx * 4];
      const float a[8] = {av0.x,av0.y,av0.z,av0.w,av1.x,av1.y,av1.z,av1.w};
      const float b[8] = {bv0.x,bv0.y,bv0.z,bv0.w,bv1.x,bv1.y,bv1.z,bv1.w};
#pragma unroll
      for (int i = 0; i < 8; ++i)
#pragma unroll
        for (int j = 0; j < 8; ++j) ov[i][j] = fmaf(a[i], b[j], ov[i][j]);
    }
  }
}

__global__ __launch_bounds__(256, 2) void k_pass2_recompute(
    const float* __restrict__ A, const float* __restrict__ B,
    const float* __restrict__ C0, const float* __restrict__ C1,
    const double* __restrict__ invSr, const double* __restrict__ invSc,
    uint4* __restrict__ cand, unsigned int* __restrict__ ctr, unsigned int cap) {
  __shared__ float SA[TK][BT];
  __shared__ float SB[TK][BT];
  __shared__ unsigned int h1[256];
  __shared__ unsigned int scn[256];
  __shared__ unsigned int sh_misc[4];
  const int tid = threadIdx.x;
  const int tx = tid & 15, ty = tid >> 4;
  const int n0 = blockIdx.y * BT, m0 = blockIdx.x * BT;

  float acc[8][8];
  inner_gemm_256(A, B, n0, m0, tid, SA, SB, acc);
  float ov[8][8];
  overlap_gemm_256(C0, C1, n0, m0, tid, SA, SB, ov);

  double isr[8], isc[8];
#pragma unroll
  for (int i = 0; i < 8; ++i) isr[i] = invSr[n0 + ty * 8 + i];
#pragma unroll
  for (int j = 0; j < 8; ++j) isc[j] = invSc[m0 + jcol(tx, j)];

  unsigned int sbits[8][8];
#pragma unroll
  for (int i = 0; i < 8; ++i)
#pragma unroll
    for (int j = 0; j < 8; ++j) {
      const double e = exp(2.0 * (double)acc[i][j] - 2.0);
      const double s = e * e * isr[i] * isc[j] * (double)ov[i][j];
      sbits[i][j] = __float_as_uint((float)s);
    }

  h1[tid] = 0;
  __syncthreads();
#pragma unroll
  for (int i = 0; i < 8; ++i)
#pragma unroll
    for (int j = 0; j < 8; ++j) atomicAdd(&h1[sbits[i][j] >> 24], 1u);
  __syncthreads();
  if (tid == 0) {
    unsigned cum = 0, cb = 0, above = 0;
    for (int b = 255; b >= 0; --b) {
      const unsigned nc = cum + h1[b];
      if (nc >= 256u) { cb = (unsigned)b; above = cum; break; }
      cum = nc;
    }
    sh_misc[0] = cb; sh_misc[1] = above;
  }
  __syncthreads();
  const unsigned cb = sh_misc[0], above = sh_misc[1];
  __syncthreads();
  h1[tid] = 0;
  __syncthreads();
#pragma unroll
  for (int i = 0; i < 8; ++i)
#pragma unroll
    for (int j = 0; j < 8; ++j)
      if ((sbits[i][j] >> 24) == cb) atomicAdd(&h1[(sbits[i][j] >> 16) & 0xFFu], 1u);
  __syncthreads();
  if (tid == 0) {
    unsigned cum = above, tb = cb << 8;
    for (int b = 255; b >= 0; --b) {
      cum += h1[b];
      if (cum >= 256u) { tb = (cb << 8) | (unsigned)b; break; }
    }
    const unsigned old = atomicMax(&ctr[2], tb);
    sh_misc[2] = tb > old ? tb : old;
  }
  __syncthreads();
  const unsigned tb16 = sh_misc[2];

  unsigned cnt = 0;
#pragma unroll
  for (int i = 0; i < 8; ++i)
#pragma unroll
    for (int j = 0; j < 8; ++j) cnt += ((sbits[i][j] >> 16) >= tb16) ? 1u : 0u;
  scn[tid] = cnt;
  __syncthreads();
  if (tid == 0) {
    unsigned run = 0;
    for (int t = 0; t < 256; ++t) { const unsigned c = scn[t]; scn[t] = run; run += c; }
    sh_misc[3] = atomicAdd(&ctr[0], run);
  }
  __syncthreads();
  unsigned pos = sh_misc[3] + scn[tid];
#pragma unroll
  for (int i = 0; i < 8; ++i)
#pragma unroll
    for (int j = 0; j < 8; ++j) {
      if ((sbits[i][j] >> 16) >= tb16) {
        if (pos < cap) {
          const double e = exp(2.0 * (double)acc[i][j] - 2.0);
          const double s = e * e * isr[i] * isc[j] * (double)ov[i][j];
          const unsigned long long db = (unsigned long long)__double_as_longlong(s);
          const unsigned idxv = ((unsigned)(n0 + ty * 8 + i) << 13) | (unsigned)(m0 + jcol(tx, j));
          cand[pos] = make_uint4((unsigned)(db & 0xFFFFFFFFull),
                                 (unsigned)(db >> 32), idxv, sbits[i][j]);
        }
        ++pos;
      }
    }
}

// ---------------------------------------------------------------------------
__global__ void k_ghist(const uint4* __restrict__ cand,
                        const unsigned int* __restrict__ ctr,
                        unsigned int cap, unsigned int* __restrict__ ghist) {
  const unsigned n = min(ctr[0], cap);
  const unsigned stride = gridDim.x * blockDim.x;
  for (unsigned i = blockIdx.x * blockDim.x + threadIdx.x; i < n; i += stride)
    atomicAdd(&ghist[cand[i].w >> 16], 1u);
}

__global__ __launch_bounds__(256) void k_thresh(const unsigned int* __restrict__ ghist,
                                                unsigned int* __restrict__ ctr) {
  __shared__ unsigned int gsum[256];
  const int tid = threadIdx.x;
  unsigned s = 0;
  const int base = tid * 256;
  for (int b = 0; b < 256; ++b) s += ghist[base + b];
  gsum[tid] = s;
  __syncthreads();
  if (tid == 0) {
    unsigned cum = 0, g = 0, above = 0;
    for (int t = 255; t >= 0; --t) {
      const unsigned nc = cum + gsum[t];
      if (nc >= 256u) { g = (unsigned)t; above = cum; break; }
      cum = nc;
    }
    unsigned tb = g * 256u, c2 = above;
    for (int b = (int)g * 256 + 255; b >= (int)g * 256; --b) {
      c2 += ghist[b];
      if (c2 >= 256u) { tb = (unsigned)b; break; }
    }
    ctr[3] = tb;
  }
}

__global__ void k_collect(const uint4* __restrict__ cand,
                          unsigned int* __restrict__ ctr,
                          unsigned int cap, uint4* __restrict__ fin) {
  const unsigned n = min(ctr[0], cap);
  const unsigned tb = ctr[3];
  const unsigned stride = gridDim.x * blockDim.x;
  for (unsigned i = blockIdx.x * blockDim.x + threadIdx.x; i < n; i += stride) {
    const uint4 c = cand[i];
    if ((c.w >> 16) >= tb) {
      const unsigned p = atomicAdd(&ctr[1], 1u);
      if (p < FCAP) fin[p] = c;
    }
  }
}

__global__ __launch_bounds__(256) void k_sort(const uint4* __restrict__ fin,
                                              const unsigned int* __restrict__ ctr,
                                              float* __restrict__ out) {
  __shared__ unsigned long long kk[FCAP];
  __shared__ unsigned int id[FCAP];
  const int tid = threadIdx.x;
  const unsigned n = min(ctr[1], FCAP);
  unsigned np2 = 256;
  while (np2 < n) np2 <<= 1;
  for (unsigned i = tid; i < np2; i += 256) {
    if (i < n) {
      const uint4 c = fin[i];
      kk[i] = ((unsigned long long)c.y << 32) | (unsigned long long)c.x;
      id[i] = c.z;
    } else {
      kk[i] = 0ull;
      id[i] = 0xFFFFFFFFu;
    }
  }
  __syncthreads();
  for (unsigned k2 = 2; k2 <= np2; k2 <<= 1) {
    for (unsigned j = k2 >> 1; j > 0; j >>= 1) {
      for (unsigned i = tid; i < np2; i += 256) {
        const unsigned l = i ^ j;
        if (l > i) {
          const unsigned long long ka = kk[i], kb = kk[l];
          const unsigned ia = id[i], ib = id[l];
          const bool aBefore = (ka > kb) || (ka == kb && ia < ib);
          const bool dsc = (i & k2) == 0;
          const bool sw = dsc ? !aBefore : aBefore;
          if (sw) { kk[i] = kb; kk[l] = ka; id[i] = ib; id[l] = ia; }
        }
      }
      __syncthreads();
    }
  }
  {
    const unsigned long long kv = kk[tid];
    const unsigned ix = id[tid];
    const double s = __longlong_as_double((long long)kv);
    out[tid]        = (float)(ix >> 13);
    out[256 + tid]  = (float)(ix & 8191u);
    out[512 + tid]  = (float)s;
  }
}

// ---------------------------------------------------------------------------
extern "C" void kernel_launch(void* const* d_in, const int* in_sizes, int n_in,
                              void* d_out, int out_size, void* d_ws, size_t ws_size,
                              hipStream_t stream) {
  (void)in_sizes; (void)n_in; (void)out_size;
  const float* ref = (const float*)d_in[0];
  const float* src = (const float*)d_in[1];
  const float* c0  = (const float*)d_in[2];
  const float* c1  = (const float*)d_in[3];
  char* ws = (char*)d_ws;
  double* Sr = (double*)(ws + WS_SR);
  double* Sc = (double*)(ws + WS_SC);
  unsigned int* ghist = (unsigned int*)(ws + WS_GHIST);
  unsigned int* ctr   = (unsigned int*)(ws + WS_CTR);
  uint4* fin   = (uint4*)(ws + WS_FINAL);
  float* inner = (float*)(ws + WS_INNER);

  const bool store = ws_size >= (size_t)WS_NEED_STORE;
  uint4* cand;
  unsigned int cap;
  if (store) {
    cand = (uint4*)(ws + WS_CAND);
    cap = (unsigned int)std::min<size_t>((ws_size - WS_CAND) / 16, (size_t)(8u << 20));
  } else {
    cand = (uint4*)(ws + WS_CANDNS);
    cap = (ws_size > WS_CANDNS + 16)
            ? (unsigned int)std::min<size_t>((ws_size - WS_CANDNS) / 16, (size_t)(8u << 20))
            : 0u;
  }

  hipMemsetAsync(d_ws, 0, (size_t)WS_FINAL, stream);  // Sr, Sc, ghist, ctr

  dim3 grid(Mm / BT, Nn / BT);
  if (store) {
    k_pass1<true><<<grid, 512, 0, stream>>>(ref, src, Sr, Sc, inner);
    k_recip<<<32, 256, 0, stream>>>(Sr, Sc);
    k_pass2_reload<<<grid, 1024, 0, stream>>>(c0, c1, Sr, Sc, inner, cand, ctr, cap);
  } else {
    k_pass1<false><<<grid, 512, 0, stream>>>(ref, src, Sr, Sc, nullptr);
    k_recip<<<32, 256, 0, stream>>>(Sr, Sc);
    k_pass2_recompute<<<grid, 256, 0, stream>>>(ref, src, c0, c1, Sr, Sc, cand, ctr, cap);
  }
  k_ghist<<<256, 256, 0, stream>>>(cand, ctr, cap, ghist);
  k_thresh<<<1, 256, 0, stream>>>(ghist, ctr);
  k_collect<<<256, 256, 0, stream>>>(cand, ctr, cap, fin);
  k_sort<<<1, 256, 0, stream>>>(fin, ctr, (float*)d_out);
}